// Round 1
// baseline (1949.107 us; speedup 1.0000x reference)
//
#include <hip/hip_runtime.h>

// CfC recurrence, persistent per-batch-group kernel.
// B=256 rows -> 16 blocks x 16 rows; each block runs all T=1024 steps on one CU.
// Weights held in VGPRs as MFMA B-fragments; LDS only for A-operands (z, [x|h]).
// t_a*1+t_b  =>  W_t = W_ta+W_tb presummed (fp32) -> one fewer head GEMM.

typedef __bf16 bf16;
typedef __bf16 bf16x8 __attribute__((ext_vector_type(8)));
typedef float  f32x4  __attribute__((ext_vector_type(4)));

#define BDIM 512

constexpr int B_  = 256;
constexpr int T_  = 1024;
constexpr int I_  = 64;
constexpr int U_  = 128;
constexpr int BB_ = 256;
constexpr int ROWS = 16;               // batch rows per block
constexpr int NBLK = B_ / ROWS;        // 16 blocks
constexpr int KO1  = (I_ + U_) / 8;    // 24 k-octets for A = [x | h]

__device__ __forceinline__ float tanh_fast(float x) {
  // tanh(x) = 1 - 2/(exp(2x)+1);  exp(2x) = exp2(x * 2*log2(e))
  float e = __builtin_amdgcn_exp2f(x * 2.8853900817779268f);
  return 1.0f - 2.0f * __builtin_amdgcn_rcpf(e + 1.0f);
}
__device__ __forceinline__ float sigmoid_fast(float x) {
  return __builtin_amdgcn_rcpf(1.0f + __builtin_amdgcn_exp2f(x * -1.4426950408889634f));
}

__global__ __launch_bounds__(BDIM, 2)
void cfc_kernel(const float* __restrict__ x,
                const float* __restrict__ Wbb,  const float* __restrict__ bbb,
                const float* __restrict__ Wff1, const float* __restrict__ bff1,
                const float* __restrict__ Wff2, const float* __restrict__ bff2,
                const float* __restrict__ Wta,  const float* __restrict__ bta,
                const float* __restrict__ Wtb,  const float* __restrict__ btb,
                float* __restrict__ out)
{
  // Fragment-linear LDS layouts: elem(m, k) = ((k>>3)*ROWS + m)*8 + (k&7)
  __shared__ __align__(16) bf16 Abuf[KO1 * ROWS * 8];   // A = [x(0:64) | h(64:192)], 6 KB
  __shared__ __align__(16) bf16 Zbuf[32  * ROWS * 8];   // z, K2=256, 8 KB

  const int tid  = threadIdx.x;
  const int w    = tid >> 6;       // wave 0..7
  const int l    = tid & 63;
  const int quad = l >> 4;
  const int l16  = l & 15;
  const int bg   = blockIdx.x;     // batch group: rows bg*16 .. bg*16+15

  // ---------------- init: build persistent B-fragments (VGPRs) ----------------
  // GEMM1: cols n = w*32 + nt*16 + l16 of W_bb [192 x 256]
  // GEMM2: u = w*16 + l16; heads: ff1, ff2, (ta+tb)  of [256 x 128] each
  const int c1 = w * 32 + l16;
  const int u  = w * 16 + l16;

  bf16x8 f1[6][2];
  #pragma unroll
  for (int ks = 0; ks < 6; ks++)
    #pragma unroll
    for (int nt = 0; nt < 2; nt++)
      #pragma unroll
      for (int j = 0; j < 8; j++) {
        int k = ks * 32 + quad * 8 + j;
        f1[ks][nt][j] = (bf16)Wbb[k * BB_ + c1 + nt * 16];
      }

  bf16x8 f2[8][3];
  #pragma unroll
  for (int ks = 0; ks < 8; ks++)
    #pragma unroll
    for (int j = 0; j < 8; j++) {
      int k = ks * 32 + quad * 8 + j;
      f2[ks][0][j] = (bf16)Wff1[k * U_ + u];
      f2[ks][1][j] = (bf16)Wff2[k * U_ + u];
      f2[ks][2][j] = (bf16)(Wta[k * U_ + u] + Wtb[k * U_ + u]);  // fp32 presum
    }

  const float bz0 = bbb[c1];
  const float bz1 = bbb[c1 + 16];
  const float bh0 = bff1[u];
  const float bh1 = bff2[u];
  const float bh2 = bta[u] + btb[u];

  // zero h-region of Abuf (k in [64,192)) : h0 = 0
  for (int idx = tid; idx < (KO1 - 8) * ROWS * 8; idx += BDIM)
    Abuf[8 * ROWS * 8 + idx] = (bf16)0.0f;

  // x staging role (thread-level): m = tid>>5, covers k = 2*kk, 2*kk+1
  const int xm  = tid >> 5;
  const int xkk = tid & 31;
  const float* xsrc = x + ((size_t)(bg * ROWS + xm) * T_) * I_ + 2 * xkk;
  bf16* xdst = &Abuf[(((2 * xkk) >> 3) * ROWS + xm) * 8 + ((2 * xkk) & 7)];

  {  // stage x(t=0)
    float2 v = *(const float2*)xsrc;
    xdst[0] = (bf16)v.x;
    xdst[1] = (bf16)v.y;
  }
  __syncthreads();

  float* outp  = out + (size_t)(bg * ROWS) * T_ * U_ + u;          // + m*T*U + t*U
  float* hlast = out + (size_t)B_ * T_ * U_ + (size_t)(bg * ROWS) * U_ + u;

  // h LDS write address pieces: k = 64+u
  const int h_oct = (64 + u) >> 3;
  const int h_sub = (64 + u) & 7;

  for (int t = 0; t < T_; ++t) {
    // prefetch x(t+1) from global (consumed after barrier 1)
    const int tn = (t + 1 < T_) ? (t + 1) : (T_ - 1);
    float2 xv = *(const float2*)(xsrc + (size_t)tn * I_);

    // ---- GEMM1: u1 = [x_t | h] @ W_bb + b_bb ----
    f32x4 az0 = { bz0, bz0, bz0, bz0 };
    f32x4 az1 = { bz1, bz1, bz1, bz1 };
    #pragma unroll
    for (int ks = 0; ks < 6; ks++) {
      bf16x8 a = *(const bf16x8*)&Abuf[((ks * 4 + quad) * ROWS + l16) * 8];
      az0 = __builtin_amdgcn_mfma_f32_16x16x32_bf16(a, f1[ks][0], az0, 0, 0, 0);
      az1 = __builtin_amdgcn_mfma_f32_16x16x32_bf16(a, f1[ks][1], az1, 0, 0, 0);
    }
    // lecun_tanh + write z fragments
    #pragma unroll
    for (int i = 0; i < 4; i++) {
      int m = quad * 4 + i;
      float z0 = 1.7159f * tanh_fast(0.666f * az0[i]);
      float z1 = 1.7159f * tanh_fast(0.666f * az1[i]);
      int c0 = c1, cB = c1 + 16;
      Zbuf[((c0 >> 3) * ROWS + m) * 8 + (c0 & 7)] = (bf16)z0;
      Zbuf[((cB >> 3) * ROWS + m) * 8 + (cB & 7)] = (bf16)z1;
    }
    __syncthreads();   // barrier 1: z ready; x(t) A-reads all done

    // stage x(t+1) into Abuf (read next step, after barrier 2)
    xdst[0] = (bf16)xv.x;
    xdst[1] = (bf16)xv.y;

    // ---- GEMM2: heads = z @ [Wff1|Wff2|Wt] + bias ----
    f32x4 a0 = { bh0, bh0, bh0, bh0 };
    f32x4 a1 = { bh1, bh1, bh1, bh1 };
    f32x4 a2 = { bh2, bh2, bh2, bh2 };
    #pragma unroll
    for (int ks = 0; ks < 8; ks++) {
      bf16x8 zf = *(const bf16x8*)&Zbuf[((ks * 4 + quad) * ROWS + l16) * 8];
      a0 = __builtin_amdgcn_mfma_f32_16x16x32_bf16(zf, f2[ks][0], a0, 0, 0, 0);
      a1 = __builtin_amdgcn_mfma_f32_16x16x32_bf16(zf, f2[ks][1], a1, 0, 0, 0);
      a2 = __builtin_amdgcn_mfma_f32_16x16x32_bf16(zf, f2[ks][2], a2, 0, 0, 0);
    }
    // ---- combine: h = ff1 + sigmoid(t)*(ff2 - ff1) ----
    #pragma unroll
    for (int i = 0; i < 4; i++) {
      int m = quad * 4 + i;
      float ff1 = tanh_fast(a0[i]);
      float ff2 = tanh_fast(a1[i]);
      float s   = sigmoid_fast(a2[i]);
      float h   = ff1 + s * (ff2 - ff1);
      outp[(size_t)m * T_ * U_ + (size_t)t * U_] = h;
      Abuf[(h_oct * ROWS + m) * 8 + h_sub] = (bf16)h;
      if (t == T_ - 1) hlast[(size_t)m * U_] = h;
    }
    __syncthreads();   // barrier 2: h ready for next GEMM1
  }
}

extern "C" void kernel_launch(void* const* d_in, const int* in_sizes, int n_in,
                              void* d_out, int out_size, void* d_ws, size_t ws_size,
                              hipStream_t stream) {
  const float* x    = (const float*)d_in[0];
  const float* Wbb  = (const float*)d_in[1];
  const float* bbb  = (const float*)d_in[2];
  const float* Wff1 = (const float*)d_in[3];
  const float* bff1 = (const float*)d_in[4];
  const float* Wff2 = (const float*)d_in[5];
  const float* bff2 = (const float*)d_in[6];
  const float* Wta  = (const float*)d_in[7];
  const float* bta  = (const float*)d_in[8];
  const float* Wtb  = (const float*)d_in[9];
  const float* btb  = (const float*)d_in[10];
  float* out = (float*)d_out;
  (void)in_sizes; (void)n_in; (void)out_size; (void)d_ws; (void)ws_size;

  hipLaunchKernelGGL(cfc_kernel, dim3(NBLK), dim3(BDIM), 0, stream,
                     x, Wbb, bbb, Wff1, bff1, Wff2, bff2, Wta, bta, Wtb, btb, out);
}

// Round 2
// 1594.932 us; speedup vs baseline: 1.2221x; 1.2221x over previous
//
#include <hip/hip_runtime.h>

// CfC recurrence, persistent per-batch-group kernel. Round 2:
//  - LDS-only barriers (s_waitcnt lgkmcnt(0) + s_barrier): global h-stores are
//    fire-and-forget, x prefetch load is never force-drained at a barrier.
//  - GEMM2 k-loop rotated per wave: own z-chunk is pre-read and pre-MFMA'd
//    BEFORE the barrier (wave wrote it itself), hiding post-barrier LDS latency.
//  - x(t+1) LDS staging moved to end of GEMM2 phase (load has ~full step in flight).
//  - h kept in regs; h_last stored once after the loop.

typedef __bf16 bf16;
typedef __bf16 bf16x8 __attribute__((ext_vector_type(8)));
typedef float  f32x4  __attribute__((ext_vector_type(4)));

#define BDIM 512

constexpr int B_  = 256;
constexpr int T_  = 1024;
constexpr int I_  = 64;
constexpr int U_  = 128;
constexpr int BB_ = 256;
constexpr int ROWS = 16;               // batch rows per block
constexpr int NBLK = B_ / ROWS;        // 16 blocks
constexpr int KO1  = (I_ + U_) / 8;    // 24 k-octets for A = [x | h]

__device__ __forceinline__ float tanh_fast(float x) {
  float e = __builtin_amdgcn_exp2f(x * 2.8853900817779268f);
  return 1.0f - 2.0f * __builtin_amdgcn_rcpf(e + 1.0f);
}
__device__ __forceinline__ float sigmoid_fast(float x) {
  return __builtin_amdgcn_rcpf(1.0f + __builtin_amdgcn_exp2f(x * -1.4426950408889634f));
}

// All cross-wave communication in the steady-state loop is through LDS.
// Global stores are never read back; the x prefetch gets its vmcnt wait at
// its use. So the barrier only needs LDS (lgkmcnt) ordering — skip the
// vmcnt(0) drain that __syncthreads() would emit.
__device__ __forceinline__ void barrier_lds() {
  asm volatile("s_waitcnt lgkmcnt(0)" ::: "memory");
  __builtin_amdgcn_s_barrier();
}

__global__ __launch_bounds__(BDIM, 2)
void cfc_kernel(const float* __restrict__ x,
                const float* __restrict__ Wbb,  const float* __restrict__ bbb,
                const float* __restrict__ Wff1, const float* __restrict__ bff1,
                const float* __restrict__ Wff2, const float* __restrict__ bff2,
                const float* __restrict__ Wta,  const float* __restrict__ bta,
                const float* __restrict__ Wtb,  const float* __restrict__ btb,
                float* __restrict__ out)
{
  // Fragment-linear LDS layouts: elem(m, k) = ((k>>3)*ROWS + m)*8 + (k&7)
  __shared__ __align__(16) bf16 Abuf[KO1 * ROWS * 8];   // A = [x(0:64) | h(64:192)], 6 KB
  __shared__ __align__(16) bf16 Zbuf[32  * ROWS * 8];   // z, K2=256, 8 KB

  const int tid  = threadIdx.x;
  const int w    = tid >> 6;       // wave 0..7
  const int l    = tid & 63;
  const int quad = l >> 4;
  const int l16  = l & 15;
  const int bg   = blockIdx.x;     // batch group: rows bg*16 .. bg*16+15

  // ---------------- init: build persistent B-fragments (VGPRs) ----------------
  const int c1 = w * 32 + l16;     // GEMM1 cols (+0 / +16)
  const int u  = w * 16 + l16;     // GEMM2 unit index

  bf16x8 f1[6][2];
  #pragma unroll
  for (int ks = 0; ks < 6; ks++)
    #pragma unroll
    for (int nt = 0; nt < 2; nt++)
      #pragma unroll
      for (int j = 0; j < 8; j++) {
        int k = ks * 32 + quad * 8 + j;
        f1[ks][nt][j] = (bf16)Wbb[k * BB_ + c1 + nt * 16];
      }

  // GEMM2 weights, wave-rotated: g2[r] holds k-chunk (w+r)&7, so r=0 is the
  // chunk this wave itself produces (pre-barrier MFMA) and indices stay
  // compile-time constant in the k-loop.
  bf16x8 g2[8][3];
  #pragma unroll
  for (int r = 0; r < 8; r++) {
    int ks = (w + r) & 7;
    #pragma unroll
    for (int j = 0; j < 8; j++) {
      int k = ks * 32 + quad * 8 + j;
      g2[r][0][j] = (bf16)Wff1[k * U_ + u];
      g2[r][1][j] = (bf16)Wff2[k * U_ + u];
      g2[r][2][j] = (bf16)(Wta[k * U_ + u] + Wtb[k * U_ + u]);  // fp32 presum
    }
  }

  const float bz0 = bbb[c1];
  const float bz1 = bbb[c1 + 16];
  const float bh0 = bff1[u];
  const float bh1 = bff2[u];
  const float bh2 = bta[u] + btb[u];

  // zero h-region of Abuf (k in [64,192)) : h0 = 0
  for (int idx = tid; idx < (KO1 - 8) * ROWS * 8; idx += BDIM)
    Abuf[8 * ROWS * 8 + idx] = (bf16)0.0f;

  // x staging role (thread-level): m = tid>>5, covers k = 2*kk, 2*kk+1
  const int xm  = tid >> 5;
  const int xkk = tid & 31;
  const float* xsrc = x + ((size_t)(bg * ROWS + xm) * T_) * I_ + 2 * xkk;
  bf16* xdst = &Abuf[(((2 * xkk) >> 3) * ROWS + xm) * 8 + ((2 * xkk) & 7)];

  {  // stage x(t=0)
    float2 v = *(const float2*)xsrc;
    xdst[0] = (bf16)v.x;
    xdst[1] = (bf16)v.y;
  }
  __syncthreads();

  float* outp  = out + (size_t)(bg * ROWS) * T_ * U_ + u;          // + m*T*U + t*U
  float* hlast = out + (size_t)B_ * T_ * U_ + (size_t)(bg * ROWS) * U_ + u;

  // h LDS write address pieces: k = 64+u
  const int h_oct = (64 + u) >> 3;
  const int h_sub = (64 + u) & 7;

  float hreg[4];

  for (int t = 0; t < T_; ++t) {
    // prefetch x(t+1) from global; consumed at END of GEMM2 phase (~full step)
    const int tn = (t + 1 < T_) ? (t + 1) : (T_ - 1);
    float2 xv = *(const float2*)(xsrc + (size_t)tn * I_);

    // ---- GEMM1: u1 = [x_t | h] @ W_bb + b_bb ----
    f32x4 az0 = { bz0, bz0, bz0, bz0 };
    f32x4 az1 = { bz1, bz1, bz1, bz1 };
    #pragma unroll
    for (int ks = 0; ks < 6; ks++) {
      bf16x8 a = *(const bf16x8*)&Abuf[((ks * 4 + quad) * ROWS + l16) * 8];
      az0 = __builtin_amdgcn_mfma_f32_16x16x32_bf16(a, f1[ks][0], az0, 0, 0, 0);
      az1 = __builtin_amdgcn_mfma_f32_16x16x32_bf16(a, f1[ks][1], az1, 0, 0, 0);
    }
    // lecun_tanh + write z fragments
    #pragma unroll
    for (int i = 0; i < 4; i++) {
      int m = quad * 4 + i;
      float z0 = 1.7159f * tanh_fast(0.666f * az0[i]);
      float z1 = 1.7159f * tanh_fast(0.666f * az1[i]);
      int c0 = c1, cB = c1 + 16;
      Zbuf[((c0 >> 3) * ROWS + m) * 8 + (c0 & 7)] = (bf16)z0;
      Zbuf[((cB >> 3) * ROWS + m) * 8 + (cB & 7)] = (bf16)z1;
    }

    // ---- GEMM2 prologue: own z-chunk (r=0, ks=w), valid pre-barrier ----
    f32x4 a0 = { bh0, bh0, bh0, bh0 };
    f32x4 a1 = { bh1, bh1, bh1, bh1 };
    f32x4 a2 = { bh2, bh2, bh2, bh2 };
    {
      bf16x8 zf = *(const bf16x8*)&Zbuf[((w * 4 + quad) * ROWS + l16) * 8];
      a0 = __builtin_amdgcn_mfma_f32_16x16x32_bf16(zf, g2[0][0], a0, 0, 0, 0);
      a1 = __builtin_amdgcn_mfma_f32_16x16x32_bf16(zf, g2[0][1], a1, 0, 0, 0);
      a2 = __builtin_amdgcn_mfma_f32_16x16x32_bf16(zf, g2[0][2], a2, 0, 0, 0);
    }
    barrier_lds();   // barrier 1: all z chunks visible; x(t) A-reads done

    // ---- GEMM2 body: remaining 7 chunks ----
    #pragma unroll
    for (int r = 1; r < 8; r++) {
      int ks = (w + r) & 7;
      bf16x8 zf = *(const bf16x8*)&Zbuf[((ks * 4 + quad) * ROWS + l16) * 8];
      a0 = __builtin_amdgcn_mfma_f32_16x16x32_bf16(zf, g2[r][0], a0, 0, 0, 0);
      a1 = __builtin_amdgcn_mfma_f32_16x16x32_bf16(zf, g2[r][1], a1, 0, 0, 0);
      a2 = __builtin_amdgcn_mfma_f32_16x16x32_bf16(zf, g2[r][2], a2, 0, 0, 0);
    }

    // ---- combine: h = ff1 + sigmoid(t)*(ff2 - ff1) ----
    #pragma unroll
    for (int i = 0; i < 4; i++) {
      int m = quad * 4 + i;
      float ff1 = tanh_fast(a0[i]);
      float ff2 = tanh_fast(a1[i]);
      float s   = sigmoid_fast(a2[i]);
      float h   = ff1 + s * (ff2 - ff1);
      hreg[i]   = h;
      outp[(size_t)m * T_ * U_ + (size_t)t * U_] = h;   // fire-and-forget
      Abuf[(h_oct * ROWS + m) * 8 + h_sub] = (bf16)h;
    }

    // stage x(t+1) into Abuf (read next step, after barrier 2)
    xdst[0] = (bf16)xv.x;
    xdst[1] = (bf16)xv.y;

    barrier_lds();   // barrier 2: h + x(t+1) ready for next GEMM1
  }

  #pragma unroll
  for (int i = 0; i < 4; i++)
    hlast[(size_t)(quad * 4 + i) * U_] = hreg[i];
}

extern "C" void kernel_launch(void* const* d_in, const int* in_sizes, int n_in,
                              void* d_out, int out_size, void* d_ws, size_t ws_size,
                              hipStream_t stream) {
  const float* x    = (const float*)d_in[0];
  const float* Wbb  = (const float*)d_in[1];
  const float* bbb  = (const float*)d_in[2];
  const float* Wff1 = (const float*)d_in[3];
  const float* bff1 = (const float*)d_in[4];
  const float* Wff2 = (const float*)d_in[5];
  const float* bff2 = (const float*)d_in[6];
  const float* Wta  = (const float*)d_in[7];
  const float* bta  = (const float*)d_in[8];
  const float* Wtb  = (const float*)d_in[9];
  const float* btb  = (const float*)d_in[10];
  float* out = (float*)d_out;
  (void)in_sizes; (void)n_in; (void)out_size; (void)d_ws; (void)ws_size;

  hipLaunchKernelGGL(cfc_kernel, dim3(NBLK), dim3(BDIM), 0, stream,
                     x, Wbb, bbb, Wff1, bff1, Wff2, bff2, Wta, bta, Wtb, btb, out);
}